// Round 4
// baseline (51.557 us; speedup 1.0000x reference)
//
#include <hip/hip_runtime.h>
#include <math.h>

#define TPB 256
#define NCLS 20
#define PPC 5
#define NB 16
#define N0 16384
#define N1 4096
#define RECSZ 36           // M[5], s[5], T1[25], cnt
#define NBLKA 1600         // 16*20*4 (scale0 quarters) + 16*20 (scale1)
#define NBLKB 640

// ---------------- kernel 1: label downsample -> packed int8 ------------------------
__global__ void downsample_labels(const int* __restrict__ tgt,
                                  char* __restrict__ lab0, char* __restrict__ lab1) {
    const int q = blockIdx.x * blockDim.x + threadIdx.x;   // 81920 quads
    if (q < 65536) {                                       // scale0: 16 * 4096 quads
        const int b = q >> 12, r = q & 4095;
        const int i = r >> 5, j0 = (r & 31) << 2;
        const int* src = tgt + b * 262144 + (i << 2) * 512;
        char4 v;
        v.x = (char)(src[(j0 + 0) << 2] - 1);
        v.y = (char)(src[(j0 + 1) << 2] - 1);
        v.z = (char)(src[(j0 + 2) << 2] - 1);
        v.w = (char)(src[(j0 + 3) << 2] - 1);
        ((char4*)lab0)[q] = v;
    } else {                                               // scale1: 16 * 1024 quads
        const int k = q - 65536;
        const int b = k >> 10, r = k & 1023;
        const int i = r >> 4, j0 = (r & 15) << 2;
        const int* src = tgt + b * 262144 + (i << 3) * 512;
        char4 v;
        v.x = (char)(src[(j0 + 0) << 3] - 1);
        v.y = (char)(src[(j0 + 1) << 3] - 1);
        v.z = (char)(src[(j0 + 2) << 3] - 1);
        v.w = (char)(src[(j0 + 3) << 3] - 1);
        ((char4*)lab1)[k] = v;
    }
}

// ---------------- kernel A: per-lane online LSE, all loads up-front, no LDS --------
__global__ __launch_bounds__(TPB, 2) void kA(const float* __restrict__ dist0,
                                             const float* __restrict__ dist1,
                                             const char* __restrict__ lab0,
                                             const char* __restrict__ lab1,
                                             float* __restrict__ recs) {
    const int blk = blockIdx.x;
    int scale, bc, split;
    if (blk < 1280) { scale = 0; bc = blk >> 2; split = blk & 3; }
    else            { scale = 1; bc = blk - 1280; split = 0; }
    const int b = bc / NCLS, c = bc % NCLS;
    const int N = scale ? N1 : N0;
    const float* dist = scale ? dist1 : dist0;
    const char* lab = (scale ? lab1 + b * N1 : lab0 + b * N0) + split * 4096;

    const int tid = threadIdx.x, lane = tid & 63, w = tid >> 6;
    const char4* lab4 = (const char4*)lab;
    const float* base = dist + (size_t)(b * 100 + c * PPC) * N + split * 4096;

    // ---- issue all 24 vector loads up-front: deep memory-level parallelism ----
    float4 A[4][PPC];
    char4 L[4];
#pragma unroll
    for (int it = 0; it < 4; ++it) {
        const int idx4 = w * 256 + it * 64 + lane;
        L[it] = lab4[idx4];
#pragma unroll
        for (int p = 0; p < PPC; ++p)
            A[it][p] = ((const float4*)(base + (size_t)p * N))[idx4];
    }

    // ---- per-lane online-rescaled state ----
    float m[PPC], s[PPC], T1[PPC * PPC];
#pragma unroll
    for (int p = 0; p < PPC; ++p) { m[p] = -INFINITY; s[p] = 0.f; }
#pragma unroll
    for (int i = 0; i < PPC * PPC; ++i) T1[i] = 0.f;
    int kcnt = 0;

#pragma unroll
    for (int it = 0; it < 4; ++it) {
#define DO_E(F)                                                                     \
        if ((int)L[it].F == c) {                                                    \
            float dv[PPC] = {A[it][0].F, A[it][1].F, A[it][2].F,                    \
                             A[it][3].F, A[it][4].F};                               \
            _Pragma("unroll")                                                       \
            for (int p = 0; p < PPC; ++p) {                                         \
                const float nm = fmaxf(m[p], dv[p]);                                \
                const float f  = __expf(m[p] - nm);   /* 0 on first touch */        \
                const float e  = __expf(dv[p] - nm);                                \
                m[p] = nm;                                                          \
                s[p] = s[p] * f + e;                                                \
                _Pragma("unroll")                                                   \
                for (int bb = 0; bb < PPC; ++bb)                                    \
                    T1[p * PPC + bb] = T1[p * PPC + bb] * f + e * dv[bb];           \
            }                                                                       \
            ++kcnt;                                                                 \
        }
        DO_E(x) DO_E(y) DO_E(z) DO_E(w)
#undef DO_E
    }

    // ---- wave reduction: max-merge, rescale, fixed shuffle trees ----
    float M[PPC];
#pragma unroll
    for (int p = 0; p < PPC; ++p) M[p] = m[p];
#pragma unroll
    for (int d = 32; d >= 1; d >>= 1)
#pragma unroll
        for (int p = 0; p < PPC; ++p) M[p] = fmaxf(M[p], __shfl_xor(M[p], d, 64));

#pragma unroll
    for (int p = 0; p < PPC; ++p) {
        const float f = (m[p] == -INFINITY) ? 0.f : __expf(m[p] - M[p]);
        s[p] *= f;
#pragma unroll
        for (int bb = 0; bb < PPC; ++bb) T1[p * PPC + bb] *= f;
    }
    float kc = (float)kcnt;
#pragma unroll
    for (int d = 32; d >= 1; d >>= 1) {
#pragma unroll
        for (int p = 0; p < PPC; ++p) s[p] += __shfl_xor(s[p], d, 64);
#pragma unroll
        for (int i = 0; i < PPC * PPC; ++i) T1[i] += __shfl_xor(T1[i], d, 64);
        kc += __shfl_xor(kc, d, 64);
    }

    if (lane == 0) {
        float* r = recs + (size_t)(blk * 4 + w) * RECSZ;
#pragma unroll
        for (int p = 0; p < PPC; ++p) { r[p] = M[p]; r[PPC + p] = s[p]; }
#pragma unroll
        for (int i = 0; i < PPC * PPC; ++i) r[10 + i] = T1[i];
        r[35] = kc;
    }
}

// ---------------- kernel B: combine records -> per-(b,c,scale) pair sums -----------
__global__ __launch_bounds__(64) void kB(const float* __restrict__ recs,
                                         float* __restrict__ psum,
                                         float* __restrict__ pcnt) {
    const int blk = blockIdx.x;
    const int lane = threadIdx.x;
    const int scale = (blk >= 320) ? 1 : 0;
    const int bc = blk - scale * 320;
    const int rbase = scale ? (5120 + bc * 4) : (bc * 16);
    const int nrec = scale ? 4 : 16;
    const int a = (lane < 25) ? lane / 5 : 0;
    const int bb = (lane < 25) ? lane % 5 : 0;

    float M = -INFINITY, cnt = 0.f;
    if (lane < 5)
        for (int r = 0; r < nrec; ++r)
            M = fmaxf(M, recs[(size_t)(rbase + r) * RECSZ + lane]);
    if (lane == 0)
        for (int r = 0; r < nrec; ++r)
            cnt += recs[(size_t)(rbase + r) * RECSZ + 35];
    cnt = __shfl(cnt, 0, 64);

    float S = 0.f;
    if (lane < 5)
        for (int r = 0; r < nrec; ++r) {
            const float* rr = recs + (size_t)(rbase + r) * RECSZ;
            S += rr[5 + lane] * expf(rr[lane] - M);   // expf(-inf - M) = 0 for empty recs
        }
    float lse = 0.f;
    if (lane < 5) lse = M + logf(S);

    const float Ma    = __shfl(M, a, 64);
    const float Sa    = __shfl(S, a, 64);
    const float lse_b = __shfl(lse, bb, 64);

    float U = 0.f;
    if (lane < 25)
        for (int r = 0; r < nrec; ++r) {
            const float* rr = recs + (size_t)(rbase + r) * RECSZ;
            U += rr[10 + lane] * expf(rr[a] - Ma);
        }
    const float C = U / Sa - lse_b;   // valid on lanes 0..24

    float tot = 0.f;
#pragma unroll
    for (int j = 0; j < PPC; ++j)
#pragma unroll
        for (int k = j + 1; k < PPC; ++k) {
            const float Ejj = __shfl(C, j * 5 + j, 64);
            const float Ekk = __shfl(C, k * 5 + k, 64);
            const float Cjk = __shfl(C, j * 5 + k, 64);
            const float Ckj = __shfl(C, k * 5 + j, 64);
            tot += expf(-0.5f * (Ejj + Ekk - Cjk - Ckj));
        }
    if (lane == 0) {
        const bool ok = (cnt >= 2.f);
        psum[blk] = ok ? tot : 0.f;
        pcnt[blk] = ok ? 10.f : 0.f;
    }
}

// ---------------- kernel C: deterministic final reduction --------------------------
__global__ void finalize_kernel(const float* __restrict__ psum,
                                const float* __restrict__ pcnt,
                                float* __restrict__ out) {
    __shared__ float rs[TPB], rc[TPB];
    const int tid = threadIdx.x;
    float s = 0.f, c = 0.f;
    for (int i = tid; i < NBLKB; i += TPB) { s += psum[i]; c += pcnt[i]; }
    rs[tid] = s; rc[tid] = c;
    __syncthreads();
    for (int off = 128; off > 0; off >>= 1) {
        if (tid < off) { rs[tid] += rs[tid + off]; rc[tid] += rc[tid + off]; }
        __syncthreads();
    }
    if (tid == 0) out[0] = (rc[0] > 0.f) ? (rs[0] / rc[0]) : 0.f;
}

extern "C" void kernel_launch(void* const* d_in, const int* in_sizes, int n_in,
                              void* d_out, int out_size, void* d_ws, size_t ws_size,
                              hipStream_t stream) {
    const float* dist0 = (const float*)d_in[0];   // [16,100,128,128] f32
    const float* dist1 = (const float*)d_in[1];   // [16,100,64,64]   f32
    const int*   tgt   = (const int*)d_in[2];     // [16,512,512]     i32
    float* out = (float*)d_out;

    char*  lab0 = (char*)d_ws;                     // 262144 B
    char*  lab1 = lab0 + 262144;                   // 65536 B
    float* recs = (float*)(lab0 + 327680);         // 6400 * 36 floats
    float* psum = recs + (size_t)NBLKA * 4 * RECSZ;
    float* pcnt = psum + NBLKB;

    downsample_labels<<<320, TPB, 0, stream>>>(tgt, lab0, lab1);
    kA<<<NBLKA, TPB, 0, stream>>>(dist0, dist1, lab0, lab1, recs);
    kB<<<NBLKB, 64, 0, stream>>>(recs, psum, pcnt);
    finalize_kernel<<<1, TPB, 0, stream>>>(psum, pcnt, out);
}